// Round 7
// baseline (48.333 us; speedup 1.0000x reference)
//
#include <hip/hip_runtime.h>
#include <hip/hip_bf16.h>
#include <math.h>

#define NB 32
#define NT 1024
#define NK 12
#define NC 64
#define NS 100
#define INV_BLOCKS (NB * NK)        // 384
#define REG_BLOCKS (NS * NK)        // 1200
#define PREP_BLOCKS (INV_BLOCKS + REG_BLOCKS)
#define MFMA_BLOCKS (NB * NK * 16)  // 6144 waves, 64 t each

typedef __attribute__((ext_vector_type(8))) short short8v;  // 8 bf16
typedef __attribute__((ext_vector_type(4))) float f32x4;

// ---------------------------------------------------------------------------
// ws: bf16 W[384*4096] (3MB) | float ldws[384] | solve_part[6144]
//     | mu_part[1200] | L_part[1200]
// ---------------------------------------------------------------------------

__device__ __forceinline__ unsigned pk2(float a, float b) {
  float2 f2{a, b};
  __hip_bfloat162 h = __float22bfloat162_rn(f2);
  union { __hip_bfloat162 h; unsigned u; } c{h};
  return c.u;
}

// Static forward substitution (L from LDS via broadcast ds_read_b128).
template <int C>
struct Row {
  static __device__ __forceinline__ void run(float (&z)[NC],
                                             const float4* __restrict__ Ls4,
                                             float& quad) {
    float a0 = z[C];
    float a1 = 0.0f;
    float diag = 0.0f;
#pragma unroll
    for (int g = 0; g <= C / 4; ++g) {
      float4 v = Ls4[C * 16 + g];
#pragma unroll
      for (int e = 0; e < 4; ++e) {
        int j = 4 * g + e;
        float ve = (e == 0) ? v.x : (e == 1) ? v.y : (e == 2) ? v.z : v.w;
        if (j < C) {
          if (j & 1)
            a1 = fmaf(-ve, z[j], a1);
          else
            a0 = fmaf(-ve, z[j], a0);
        } else if (j == C) {
          diag = ve;
        }
      }
    }
    float zc = (a0 + a1) * __builtin_amdgcn_rcpf(diag);
    z[C] = zc;
    quad = fmaf(zc, zc, quad);
    Row<C + 1>::run(z, Ls4, quad);
  }
};
template <>
struct Row<NC> {
  static __device__ __forceinline__ void run(float (&)[NC], const float4*,
                                             float&) {}
};

// Blocks [0,384): invert W=L^{-1} (bf16) + logdet.  Blocks [384,1584): reg.
__global__ __launch_bounds__(256) void prep_kernel(
    const float* __restrict__ mu_pop, const float* __restrict__ L_pop,
    const float* __restrict__ mu_subj, const float* __restrict__ L_subj,
    const int* __restrict__ sids, unsigned short* __restrict__ Wws,
    float* __restrict__ ldws, float* __restrict__ mu_part,
    float* __restrict__ L_part) {
  __shared__ float smem[NC * (NC + 1)];  // 16.6 KB: L (4096f) then W^T padded
  int bid = blockIdx.x;
  int tid = threadIdx.x;

  if (bid < INV_BLOCKS) {
    int b = bid / NK, k = bid % NK;
    int sid = __builtin_amdgcn_readfirstlane(sids[b]);
    const float4* Lg =
        reinterpret_cast<const float4*>(L_subj + (size_t)(sid * NK + k) * NC * NC);
    float4* Ls4 = reinterpret_cast<float4*>(smem);
#pragma unroll
    for (int i = 0; i < 4; ++i) Ls4[tid + 256 * i] = Lg[tid + 256 * i];
    __syncthreads();

    int j = tid & 63;
    int wv = tid >> 6;
    float z[NC];
    float ld = 0.0f;
    if (wv == 0) {
      ld = __logf(smem[j * (NC + 1)]);  // diag: j*64+j
#pragma unroll
      for (int off = 1; off < 64; off <<= 1) ld += __shfl_xor(ld, off);
#pragma unroll
      for (int c = 0; c < NC; ++c) z[c] = (c == j) ? 1.0f : 0.0f;
      float dummy = 0.0f;
      Row<0>::run(z, reinterpret_cast<const float4*>(smem), dummy);
    }
    __syncthreads();  // substitution done; L no longer needed
    if (wv == 0) {
#pragma unroll
      for (int rr = 0; rr < NC; ++rr) smem[rr * (NC + 1) + j] = z[rr];
      if (j == 0) ldws[bid] = ld;
    }
    __syncthreads();
    unsigned* dst = reinterpret_cast<unsigned*>(Wws + (size_t)bid * NC * NC);
#pragma unroll
    for (int i = 0; i < 8; ++i) {
      int flat = i * 256 + tid;  // [0,2048)
      int rr = flat >> 5;
      int c2 = flat & 31;
      dst[flat] = pk2(smem[rr * (NC + 1) + 2 * c2], smem[rr * (NC + 1) + 2 * c2 + 1]);
    }
    return;
  }

  // ---- reg part ----
  int rb = bid - INV_BLOCKS;
  int s = rb / NK, k = rb % NK;
  int lane = tid & 63;
  int sv = sids[lane & 31];
  bool pres = __ballot(sv == s) != 0ull;
  if (!pres) {
    if (tid == 0) {
      mu_part[rb] = 0.0f;
      L_part[rb] = 0.0f;
    }
    return;
  }

  const float4* Ls =
      reinterpret_cast<const float4*>(L_subj + (size_t)(s * NK + k) * NC * NC);
  const float4* Lp = reinterpret_cast<const float4*>(L_pop + (size_t)k * NC * NC);
  float sl = 0.0f;
#pragma unroll
  for (int i = 0; i < 4; ++i) {
    int idx = tid + i * 256;
    float4 a = Ls[idx], p = Lp[idx];
    float dx = a.x - p.x, dy = a.y - p.y, dz = a.z - p.z, dw = a.w - p.w;
    sl += dx * dx + dy * dy + dz * dz + dw * dw;
  }
  float sm = 0.0f;
  if (tid < NC) {
    float d = mu_subj[(size_t)(s * NK + k) * NC + tid] - mu_pop[k * NC + tid];
    sm = d * d;
  }
#pragma unroll
  for (int off = 1; off < 64; off <<= 1) {
    sl += __shfl_xor(sl, off);
    sm += __shfl_xor(sm, off);
  }
  if (lane == 0) {
    smem[tid >> 6] = sl;
    smem[4 + (tid >> 6)] = sm;
  }
  __syncthreads();
  if (tid == 0) {
    mu_part[rb] = smem[4] + smem[5] + smem[6] + smem[7];
    L_part[rb] = smem[0] + smem[1] + smem[2] + smem[3];
  }
}

// One wave per (b,k,1/16th of t). Z = W (x - mu) via mfma_f32_16x16x32_bf16.
__global__ __launch_bounds__(64) void mfma_kernel(
    const float* __restrict__ data,      // (B,T,C)
    const float* __restrict__ mu_subj,   // (S,K,C)
    const float* __restrict__ gamma,     // (B,T,K)
    const int*   __restrict__ sids,      // (B,1)
    const unsigned short* __restrict__ Wws,
    const float* __restrict__ ldws,
    float* __restrict__ solve_part) {
  // XCD-aware decode: 192 (k,q) slices of 4 b's per XCD -> data/gamma/W L2-fit
  int blk = blockIdx.x;
  int x   = blk & 7;
  int r   = blk >> 3;           // [0,768)
  int b   = (r / 192) * 8 + x;  // [0,32)
  int rem = r % 192;
  int k   = rem >> 4;           // [0,12)
  int q   = rem & 15;           // 64 t each
  int lane = threadIdx.x;
  int g = lane >> 4;            // k-group 0..3
  int m = lane & 15;            // row (A) / col (B,C)

  int sid = __builtin_amdgcn_readfirstlane(sids[b]);
  float ld4 = 0.25f * ldws[b * NK + k];  // each t's ld counted by 4 lanes

  int t0 = q * 64;
  float gpre[4];
#pragma unroll
  for (int tt = 0; tt < 4; ++tt)
    gpre[tt] = gamma[((size_t)(b * NT + t0 + tt * 16 + m)) * NK + k];

  const unsigned short* Wp = Wws + (size_t)(b * NK + k) * NC * NC;
  short8v afrag[4][2];
#pragma unroll
  for (int ct = 0; ct < 4; ++ct)
#pragma unroll
    for (int kk = 0; kk < 2; ++kk)
      afrag[ct][kk] = *reinterpret_cast<const short8v*>(
          Wp + (ct * 16 + m) * NC + kk * 32 + g * 8);

  const float* mu = mu_subj + (size_t)(sid * NK + k) * NC;
  float4 mu0a = *reinterpret_cast<const float4*>(mu + g * 8);
  float4 mu0b = *reinterpret_cast<const float4*>(mu + g * 8 + 4);
  float4 mu1a = *reinterpret_cast<const float4*>(mu + 32 + g * 8);
  float4 mu1b = *reinterpret_cast<const float4*>(mu + 32 + g * 8 + 4);

  float wacc = 0.0f;
#pragma unroll
  for (int tt = 0; tt < 4; ++tt) {
    int t = t0 + tt * 16 + m;
    const float* dp = data + ((size_t)(b * NT + t)) * NC;

    union { unsigned u[4]; short8v v; } ub0, ub1;
    {
      const float4* dv = reinterpret_cast<const float4*>(dp + g * 8);
      float4 v0 = dv[0], v1 = dv[1];
      ub0.u[0] = pk2(v0.x - mu0a.x, v0.y - mu0a.y);
      ub0.u[1] = pk2(v0.z - mu0a.z, v0.w - mu0a.w);
      ub0.u[2] = pk2(v1.x - mu0b.x, v1.y - mu0b.y);
      ub0.u[3] = pk2(v1.z - mu0b.z, v1.w - mu0b.w);
    }
    {
      const float4* dv = reinterpret_cast<const float4*>(dp + 32 + g * 8);
      float4 v0 = dv[0], v1 = dv[1];
      ub1.u[0] = pk2(v0.x - mu1a.x, v0.y - mu1a.y);
      ub1.u[1] = pk2(v0.z - mu1a.z, v0.w - mu1a.w);
      ub1.u[2] = pk2(v1.x - mu1b.x, v1.y - mu1b.y);
      ub1.u[3] = pk2(v1.z - mu1b.z, v1.w - mu1b.w);
    }

    f32x4 acc0 = {0.f, 0.f, 0.f, 0.f}, acc1 = acc0, acc2 = acc0, acc3 = acc0;
    acc0 = __builtin_amdgcn_mfma_f32_16x16x32_bf16(afrag[0][0], ub0.v, acc0, 0, 0, 0);
    acc0 = __builtin_amdgcn_mfma_f32_16x16x32_bf16(afrag[0][1], ub1.v, acc0, 0, 0, 0);
    acc1 = __builtin_amdgcn_mfma_f32_16x16x32_bf16(afrag[1][0], ub0.v, acc1, 0, 0, 0);
    acc1 = __builtin_amdgcn_mfma_f32_16x16x32_bf16(afrag[1][1], ub1.v, acc1, 0, 0, 0);
    acc2 = __builtin_amdgcn_mfma_f32_16x16x32_bf16(afrag[2][0], ub0.v, acc2, 0, 0, 0);
    acc2 = __builtin_amdgcn_mfma_f32_16x16x32_bf16(afrag[2][1], ub1.v, acc2, 0, 0, 0);
    acc3 = __builtin_amdgcn_mfma_f32_16x16x32_bf16(afrag[3][0], ub0.v, acc3, 0, 0, 0);
    acc3 = __builtin_amdgcn_mfma_f32_16x16x32_bf16(afrag[3][1], ub1.v, acc3, 0, 0, 0);

    float s = 0.0f;
#pragma unroll
    for (int e = 0; e < 4; ++e) {
      s = fmaf(acc0[e], acc0[e], s);
      s = fmaf(acc1[e], acc1[e], s);
      s = fmaf(acc2[e], acc2[e], s);
      s = fmaf(acc3[e], acc3[e], s);
    }
    wacc = fmaf(gpre[tt], fmaf(-0.5f, s, -ld4), wacc);
  }

#pragma unroll
  for (int off = 1; off < 64; off <<= 1) wacc += __shfl_xor(wacc, off);
  if (lane == 0) solve_part[blockIdx.x] = wacc;
}

// Deterministic reduce + distinct-subject count + final combine.
__global__ __launch_bounds__(256) void finalize_kernel(
    const float* __restrict__ solve_part, const float* __restrict__ mu_part,
    const float* __restrict__ L_part, const int* __restrict__ sids,
    float* __restrict__ out) {
  __shared__ int ssv[32];
  __shared__ double r0[4], r1[4], r2[4];
  __shared__ int r3[4];
  int tid = threadIdx.x;
  if (tid < 32) ssv[tid] = sids[tid];
  __syncthreads();

  double s_ll = 0.0, s_mu = 0.0, s_L = 0.0;
  for (int i = tid; i < MFMA_BLOCKS; i += 256) s_ll += (double)solve_part[i];
  for (int i = tid; i < REG_BLOCKS; i += 256) {
    s_mu += (double)mu_part[i];
    s_L += (double)L_part[i];
  }
  int cnt = 0;
  if (tid < NS) {
    for (int i = 0; i < 32; ++i)
      if (ssv[i] == tid) { cnt = 1; break; }
  }
#pragma unroll
  for (int off = 1; off < 64; off <<= 1) {
    s_ll += __shfl_xor(s_ll, off);
    s_mu += __shfl_xor(s_mu, off);
    s_L += __shfl_xor(s_L, off);
    cnt += __shfl_xor(cnt, off);
  }
  int lane = tid & 63;
  if (lane == 0) {
    r0[tid >> 6] = s_ll;
    r1[tid >> 6] = s_mu;
    r2[tid >> 6] = s_L;
    r3[tid >> 6] = cnt;
  }
  __syncthreads();
  if (tid == 0) {
    double ll_sum = r0[0] + r0[1] + r0[2] + r0[3];
    double mu_reg = r1[0] + r1[1] + r1[2] + r1[3];
    double L_reg = r2[0] + r2[1] + r2[2] + r2[3];
    int c = r3[0] + r3[1] + r3[2] + r3[3];
    double c0 = 0.5 * (double)NC * log(2.0 * M_PI);
    double ll = ll_sum / (double)NB - (double)NT * c0;
    double reg = (0.5 * mu_reg + 0.5 * L_reg) * ((double)c / (double)NS);
    out[0] = (float)(-ll + reg);
  }
}

extern "C" void kernel_launch(void* const* d_in, const int* in_sizes, int n_in,
                              void* d_out, int out_size, void* d_ws,
                              size_t ws_size, hipStream_t stream) {
  const float* data    = (const float*)d_in[0];
  const float* mu_pop  = (const float*)d_in[1];
  const float* L_pop   = (const float*)d_in[2];
  const float* mu_subj = (const float*)d_in[3];
  const float* L_subj  = (const float*)d_in[4];
  const float* gamma   = (const float*)d_in[5];
  const int*   sids    = (const int*)d_in[6];
  float* out = (float*)d_out;

  unsigned short* Wws = (unsigned short*)d_ws;  // 3 MB
  float* ldws       = (float*)((char*)d_ws + (size_t)INV_BLOCKS * NC * NC * 2);
  float* solve_part = ldws + INV_BLOCKS;
  float* mu_part    = solve_part + MFMA_BLOCKS;
  float* L_part     = mu_part + REG_BLOCKS;

  hipLaunchKernelGGL(prep_kernel, dim3(PREP_BLOCKS), dim3(256), 0, stream,
                     mu_pop, L_pop, mu_subj, L_subj, sids, Wws, ldws, mu_part,
                     L_part);
  hipLaunchKernelGGL(mfma_kernel, dim3(MFMA_BLOCKS), dim3(64), 0, stream,
                     data, mu_subj, gamma, sids, Wws, ldws, solve_part);
  hipLaunchKernelGGL(finalize_kernel, dim3(1), dim3(256), 0, stream,
                     solve_part, mu_part, L_part, sids, out);
}

// Round 8
// 42.851 us; speedup vs baseline: 1.1279x; 1.1279x over previous
//
#include <hip/hip_runtime.h>
#include <hip/hip_bf16.h>
#include <math.h>

#define NB 32
#define NT 1024
#define NK 12
#define NC 64
#define NS 100
#define INV_BLOCKS (NB * NK)        // 384
#define REG_BLOCKS (NS * NK)        // 1200
#define PREP_BLOCKS (INV_BLOCKS + REG_BLOCKS)
#define MFMA_BLOCKS (NB * NK * 8)   // 3072 waves, 128 t each (r6 config: best)

typedef __attribute__((ext_vector_type(8))) short short8v;  // 8 bf16
typedef __attribute__((ext_vector_type(4))) float f32x4;

// ---------------------------------------------------------------------------
// ws: bf16 W[384*4096] (3MB) | float ldws[384] | solve_part[3072]
//     | mu_part[1200] | L_part[1200]
// ---------------------------------------------------------------------------

__device__ __forceinline__ unsigned pk2(float a, float b) {
  float2 f2{a, b};
  __hip_bfloat162 h = __float22bfloat162_rn(f2);
  union { __hip_bfloat162 h; unsigned u; } c{h};
  return c.u;
}

// Static forward substitution (L from LDS via broadcast ds_read_b128).
template <int C>
struct Row {
  static __device__ __forceinline__ void run(float (&z)[NC],
                                             const float4* __restrict__ Ls4,
                                             float& quad) {
    float a0 = z[C];
    float a1 = 0.0f;
    float diag = 0.0f;
#pragma unroll
    for (int g = 0; g <= C / 4; ++g) {
      float4 v = Ls4[C * 16 + g];
#pragma unroll
      for (int e = 0; e < 4; ++e) {
        int j = 4 * g + e;
        float ve = (e == 0) ? v.x : (e == 1) ? v.y : (e == 2) ? v.z : v.w;
        if (j < C) {
          if (j & 1)
            a1 = fmaf(-ve, z[j], a1);
          else
            a0 = fmaf(-ve, z[j], a0);
        } else if (j == C) {
          diag = ve;
        }
      }
    }
    float zc = (a0 + a1) * __builtin_amdgcn_rcpf(diag);
    z[C] = zc;
    quad = fmaf(zc, zc, quad);
    Row<C + 1>::run(z, Ls4, quad);
  }
};
template <>
struct Row<NC> {
  static __device__ __forceinline__ void run(float (&)[NC], const float4*,
                                             float&) {}
};

// Blocks [0,384): invert W=L^{-1} (bf16) + logdet.  Blocks [384,1584): reg.
__global__ __launch_bounds__(256) void prep_kernel(
    const float* __restrict__ mu_pop, const float* __restrict__ L_pop,
    const float* __restrict__ mu_subj, const float* __restrict__ L_subj,
    const int* __restrict__ sids, unsigned short* __restrict__ Wws,
    float* __restrict__ ldws, float* __restrict__ mu_part,
    float* __restrict__ L_part) {
  __shared__ float smem[NC * (NC + 1)];  // 16.6 KB: L (4096f) then W^T padded
  int bid = blockIdx.x;
  int tid = threadIdx.x;

  if (bid < INV_BLOCKS) {
    int b = bid / NK, k = bid % NK;
    int sid = __builtin_amdgcn_readfirstlane(sids[b]);
    const float4* Lg =
        reinterpret_cast<const float4*>(L_subj + (size_t)(sid * NK + k) * NC * NC);
    float4* Ls4 = reinterpret_cast<float4*>(smem);
#pragma unroll
    for (int i = 0; i < 4; ++i) Ls4[tid + 256 * i] = Lg[tid + 256 * i];
    __syncthreads();

    int j = tid & 63;
    int wv = tid >> 6;
    float z[NC];
    float ld = 0.0f;
    if (wv == 0) {
      ld = __logf(smem[j * (NC + 1)]);  // diag: j*64+j
#pragma unroll
      for (int off = 1; off < 64; off <<= 1) ld += __shfl_xor(ld, off);
#pragma unroll
      for (int c = 0; c < NC; ++c) z[c] = (c == j) ? 1.0f : 0.0f;
      float dummy = 0.0f;
      Row<0>::run(z, reinterpret_cast<const float4*>(smem), dummy);
    }
    __syncthreads();  // substitution done; L no longer needed
    if (wv == 0) {
#pragma unroll
      for (int rr = 0; rr < NC; ++rr) smem[rr * (NC + 1) + j] = z[rr];
      if (j == 0) ldws[bid] = ld;
    }
    __syncthreads();
    unsigned* dst = reinterpret_cast<unsigned*>(Wws + (size_t)bid * NC * NC);
#pragma unroll
    for (int i = 0; i < 8; ++i) {
      int flat = i * 256 + tid;  // [0,2048)
      int rr = flat >> 5;
      int c2 = flat & 31;
      dst[flat] = pk2(smem[rr * (NC + 1) + 2 * c2], smem[rr * (NC + 1) + 2 * c2 + 1]);
    }
    return;
  }

  // ---- reg part ----
  int rb = bid - INV_BLOCKS;
  int s = rb / NK, k = rb % NK;
  int lane = tid & 63;
  int sv = sids[lane & 31];
  bool pres = __ballot(sv == s) != 0ull;
  if (!pres) {
    if (tid == 0) {
      mu_part[rb] = 0.0f;
      L_part[rb] = 0.0f;
    }
    return;
  }

  const float4* Ls =
      reinterpret_cast<const float4*>(L_subj + (size_t)(s * NK + k) * NC * NC);
  const float4* Lp = reinterpret_cast<const float4*>(L_pop + (size_t)k * NC * NC);
  float sl = 0.0f;
#pragma unroll
  for (int i = 0; i < 4; ++i) {
    int idx = tid + i * 256;
    float4 a = Ls[idx], p = Lp[idx];
    float dx = a.x - p.x, dy = a.y - p.y, dz = a.z - p.z, dw = a.w - p.w;
    sl += dx * dx + dy * dy + dz * dz + dw * dw;
  }
  float sm = 0.0f;
  if (tid < NC) {
    float d = mu_subj[(size_t)(s * NK + k) * NC + tid] - mu_pop[k * NC + tid];
    sm = d * d;
  }
#pragma unroll
  for (int off = 1; off < 64; off <<= 1) {
    sl += __shfl_xor(sl, off);
    sm += __shfl_xor(sm, off);
  }
  if (lane == 0) {
    smem[tid >> 6] = sl;
    smem[4 + (tid >> 6)] = sm;
  }
  __syncthreads();
  if (tid == 0) {
    mu_part[rb] = smem[4] + smem[5] + smem[6] + smem[7];
    L_part[rb] = smem[0] + smem[1] + smem[2] + smem[3];
  }
}

// One wave per (b,k,octile of t). Z = W (x - mu) via mfma_f32_16x16x32_bf16.
__global__ __launch_bounds__(64) void mfma_kernel(
    const float* __restrict__ data,      // (B,T,C)
    const float* __restrict__ mu_subj,   // (S,K,C)
    const float* __restrict__ gamma,     // (B,T,K)
    const int*   __restrict__ sids,      // (B,1)
    const unsigned short* __restrict__ Wws,
    const float* __restrict__ ldws,
    float* __restrict__ solve_part) {
  // XCD-aware decode: 96 (k,q) blocks of 4 b's per XCD -> data/gamma/W L2-fit
  int blk = blockIdx.x;
  int x   = blk & 7;
  int r   = blk >> 3;          // [0,384)
  int b   = (r / 96) * 8 + x;  // [0,32)
  int rem = r % 96;
  int k   = rem >> 3;          // [0,12)
  int q   = rem & 7;           // octile: 128 t each
  int lane = threadIdx.x;
  int g = lane >> 4;           // k-group 0..3
  int m = lane & 15;           // row (A) / col (B,C)

  int sid = __builtin_amdgcn_readfirstlane(sids[b]);
  float ld4 = 0.25f * ldws[b * NK + k];  // each t's ld counted by 4 lanes

  int t0 = q * 128;
  // gamma preload: 8 independent loads, latency hidden
  float gpre[8];
#pragma unroll
  for (int tt = 0; tt < 8; ++tt)
    gpre[tt] = gamma[((size_t)(b * NT + t0 + tt * 16 + m)) * NK + k];

  // A-frags: W rows (bf16, row-major, contiguous per-lane 16B)
  const unsigned short* Wp = Wws + (size_t)(b * NK + k) * NC * NC;
  short8v afrag[4][2];
#pragma unroll
  for (int ct = 0; ct < 4; ++ct)
#pragma unroll
    for (int kk = 0; kk < 2; ++kk)
      afrag[ct][kk] = *reinterpret_cast<const short8v*>(
          Wp + (ct * 16 + m) * NC + kk * 32 + g * 8);

  const float* mu = mu_subj + (size_t)(sid * NK + k) * NC;
  float4 mu0a = *reinterpret_cast<const float4*>(mu + g * 8);
  float4 mu0b = *reinterpret_cast<const float4*>(mu + g * 8 + 4);
  float4 mu1a = *reinterpret_cast<const float4*>(mu + 32 + g * 8);
  float4 mu1b = *reinterpret_cast<const float4*>(mu + 32 + g * 8 + 4);

  float wacc = 0.0f;
#pragma unroll
  for (int tt = 0; tt < 8; ++tt) {
    int t = t0 + tt * 16 + m;
    const float* dp = data + ((size_t)(b * NT + t)) * NC;

    union { unsigned u[4]; short8v v; } ub0, ub1;
    {
      const float4* dv = reinterpret_cast<const float4*>(dp + g * 8);
      float4 v0 = dv[0], v1 = dv[1];
      ub0.u[0] = pk2(v0.x - mu0a.x, v0.y - mu0a.y);
      ub0.u[1] = pk2(v0.z - mu0a.z, v0.w - mu0a.w);
      ub0.u[2] = pk2(v1.x - mu0b.x, v1.y - mu0b.y);
      ub0.u[3] = pk2(v1.z - mu0b.z, v1.w - mu0b.w);
    }
    {
      const float4* dv = reinterpret_cast<const float4*>(dp + 32 + g * 8);
      float4 v0 = dv[0], v1 = dv[1];
      ub1.u[0] = pk2(v0.x - mu1a.x, v0.y - mu1a.y);
      ub1.u[1] = pk2(v0.z - mu1a.z, v0.w - mu1a.w);
      ub1.u[2] = pk2(v1.x - mu1b.x, v1.y - mu1b.y);
      ub1.u[3] = pk2(v1.z - mu1b.z, v1.w - mu1b.w);
    }

    f32x4 acc0 = {0.f, 0.f, 0.f, 0.f}, acc1 = acc0, acc2 = acc0, acc3 = acc0;
    acc0 = __builtin_amdgcn_mfma_f32_16x16x32_bf16(afrag[0][0], ub0.v, acc0, 0, 0, 0);
    acc0 = __builtin_amdgcn_mfma_f32_16x16x32_bf16(afrag[0][1], ub1.v, acc0, 0, 0, 0);
    acc1 = __builtin_amdgcn_mfma_f32_16x16x32_bf16(afrag[1][0], ub0.v, acc1, 0, 0, 0);
    acc1 = __builtin_amdgcn_mfma_f32_16x16x32_bf16(afrag[1][1], ub1.v, acc1, 0, 0, 0);
    acc2 = __builtin_amdgcn_mfma_f32_16x16x32_bf16(afrag[2][0], ub0.v, acc2, 0, 0, 0);
    acc2 = __builtin_amdgcn_mfma_f32_16x16x32_bf16(afrag[2][1], ub1.v, acc2, 0, 0, 0);
    acc3 = __builtin_amdgcn_mfma_f32_16x16x32_bf16(afrag[3][0], ub0.v, acc3, 0, 0, 0);
    acc3 = __builtin_amdgcn_mfma_f32_16x16x32_bf16(afrag[3][1], ub1.v, acc3, 0, 0, 0);

    // per-lane partial: 16 of the 64 rows of col t. gamma & ld folded
    // linearly (4 lanes per t share gamma; ld4 pre-scaled by 1/4).
    float s = 0.0f;
#pragma unroll
    for (int e = 0; e < 4; ++e) {
      s = fmaf(acc0[e], acc0[e], s);
      s = fmaf(acc1[e], acc1[e], s);
      s = fmaf(acc2[e], acc2[e], s);
      s = fmaf(acc3[e], acc3[e], s);
    }
    wacc = fmaf(gpre[tt], fmaf(-0.5f, s, -ld4), wacc);
  }

#pragma unroll
  for (int off = 1; off < 64; off <<= 1) wacc += __shfl_xor(wacc, off);
  if (lane == 0) solve_part[blockIdx.x] = wacc;
}

// Deterministic reduce + distinct-subject count + final combine.
__global__ __launch_bounds__(256) void finalize_kernel(
    const float* __restrict__ solve_part, const float* __restrict__ mu_part,
    const float* __restrict__ L_part, const int* __restrict__ sids,
    float* __restrict__ out) {
  __shared__ int ssv[32];
  __shared__ double r0[4], r1[4], r2[4];
  __shared__ int r3[4];
  int tid = threadIdx.x;
  if (tid < 32) ssv[tid] = sids[tid];
  __syncthreads();

  double s_ll = 0.0, s_mu = 0.0, s_L = 0.0;
  for (int i = tid; i < MFMA_BLOCKS; i += 256) s_ll += (double)solve_part[i];
  for (int i = tid; i < REG_BLOCKS; i += 256) {
    s_mu += (double)mu_part[i];
    s_L += (double)L_part[i];
  }
  int cnt = 0;
  if (tid < NS) {
    for (int i = 0; i < 32; ++i)
      if (ssv[i] == tid) { cnt = 1; break; }
  }
#pragma unroll
  for (int off = 1; off < 64; off <<= 1) {
    s_ll += __shfl_xor(s_ll, off);
    s_mu += __shfl_xor(s_mu, off);
    s_L += __shfl_xor(s_L, off);
    cnt += __shfl_xor(cnt, off);
  }
  int lane = tid & 63;
  if (lane == 0) {
    r0[tid >> 6] = s_ll;
    r1[tid >> 6] = s_mu;
    r2[tid >> 6] = s_L;
    r3[tid >> 6] = cnt;
  }
  __syncthreads();
  if (tid == 0) {
    double ll_sum = r0[0] + r0[1] + r0[2] + r0[3];
    double mu_reg = r1[0] + r1[1] + r1[2] + r1[3];
    double L_reg = r2[0] + r2[1] + r2[2] + r2[3];
    int c = r3[0] + r3[1] + r3[2] + r3[3];
    double c0 = 0.5 * (double)NC * log(2.0 * M_PI);
    double ll = ll_sum / (double)NB - (double)NT * c0;
    double reg = (0.5 * mu_reg + 0.5 * L_reg) * ((double)c / (double)NS);
    out[0] = (float)(-ll + reg);
  }
}

extern "C" void kernel_launch(void* const* d_in, const int* in_sizes, int n_in,
                              void* d_out, int out_size, void* d_ws,
                              size_t ws_size, hipStream_t stream) {
  const float* data    = (const float*)d_in[0];
  const float* mu_pop  = (const float*)d_in[1];
  const float* L_pop   = (const float*)d_in[2];
  const float* mu_subj = (const float*)d_in[3];
  const float* L_subj  = (const float*)d_in[4];
  const float* gamma   = (const float*)d_in[5];
  const int*   sids    = (const int*)d_in[6];
  float* out = (float*)d_out;

  unsigned short* Wws = (unsigned short*)d_ws;  // 3 MB
  float* ldws       = (float*)((char*)d_ws + (size_t)INV_BLOCKS * NC * NC * 2);
  float* solve_part = ldws + INV_BLOCKS;
  float* mu_part    = solve_part + MFMA_BLOCKS;
  float* L_part     = mu_part + REG_BLOCKS;

  hipLaunchKernelGGL(prep_kernel, dim3(PREP_BLOCKS), dim3(256), 0, stream,
                     mu_pop, L_pop, mu_subj, L_subj, sids, Wws, ldws, mu_part,
                     L_part);
  hipLaunchKernelGGL(mfma_kernel, dim3(MFMA_BLOCKS), dim3(64), 0, stream,
                     data, mu_subj, gamma, sids, Wws, ldws, solve_part);
  hipLaunchKernelGGL(finalize_kernel, dim3(1), dim3(256), 0, stream,
                     solve_part, mu_part, L_part, sids, out);
}